// Round 13
// baseline (181.618 us; speedup 1.0000x reference)
//
#include <hip/hip_runtime.h>
#include <hip/hip_bf16.h>

// Problem constants (match setup_inputs): B=2, N=512, D=128, H=256.
#define BB 2
#define NN 512
#define DD 128
#define HH 256

typedef __attribute__((ext_vector_type(4))) float    f32x4;
typedef __attribute__((ext_vector_type(8))) _Float16 f16x8;  // 4 VGPRs
typedef __attribute__((ext_vector_type(4))) int      i32x4;

union F16x8 { f16x8 v; i32x4 i; };

// ---------------------------------------------------------------------------
// Stage 1 (+W2 prep in extra blocks):
//   hA[b,n,h] = f16(b1[h] + sum_d PhiA*W1[:D]);  hB = f16(PhiB*W1[D:])
//   W2t[col][k] = f16(W2[k][col])
// ---------------------------------------------------------------------------
#define S1_ROWS 8
#define S1_BLOCKS (2 * (BB * NN) / S1_ROWS)  // 256
__global__ __launch_bounds__(256) void stage1(
    const float* __restrict__ PhiA, const float* __restrict__ PhiB,
    const float* __restrict__ W1,  const float* __restrict__ b1,
    const float* __restrict__ W2,
    _Float16* __restrict__ hA, _Float16* __restrict__ hB,
    _Float16* __restrict__ W2t) {
  if (blockIdx.x >= S1_BLOCKS) {  // W2 transpose+cast: 8 blocks
    const int bid2 = blockIdx.x - S1_BLOCKS;       // 0..7
    const int col  = bid2 * 32 + (threadIdx.x >> 3);
    const int k0   = (threadIdx.x & 7) * 32;
#pragma unroll
    for (int j = 0; j < 32; j++)
      W2t[col * HH + k0 + j] = (_Float16)W2[(k0 + j) * HH + col];
    return;
  }
  __shared__ float phis[S1_ROWS * DD];  // 4 KB
  const int side = blockIdx.x & 1;
  const int row0 = (blockIdx.x >> 1) * S1_ROWS;
  const float* Phi = side ? PhiB : PhiA;
  const float* W   = W1 + side * DD * HH;
  ((f32x4*)phis)[threadIdx.x] =
      ((const f32x4*)(Phi + (size_t)row0 * DD))[threadIdx.x];
  __syncthreads();
  const int h = threadIdx.x;
  float acc[S1_ROWS];
#pragma unroll
  for (int i = 0; i < S1_ROWS; i++) acc[i] = 0.f;
  for (int d0 = 0; d0 < DD; d0 += 4) {
    const float w0 = W[(d0 + 0) * HH + h];
    const float w1 = W[(d0 + 1) * HH + h];
    const float w2 = W[(d0 + 2) * HH + h];
    const float w3 = W[(d0 + 3) * HH + h];
#pragma unroll
    for (int i = 0; i < S1_ROWS; i++) {
      f32x4 ph = *(const f32x4*)&phis[i * DD + d0];
      acc[i] = fmaf(ph.x, w0, acc[i]);
      acc[i] = fmaf(ph.y, w1, acc[i]);
      acc[i] = fmaf(ph.z, w2, acc[i]);
      acc[i] = fmaf(ph.w, w3, acc[i]);
    }
  }
  const float bias = side ? 0.f : b1[h];
  _Float16* o = (side ? hB : hA) + (size_t)row0 * HH + h;
#pragma unroll
  for (int i = 0; i < S1_ROWS; i++) o[i * HH] = (_Float16)(acc[i] + bias);
}

// ---------------------------------------------------------------------------
// Main fused kernel: 256 threads = 4 waves; wave w owns cols [w*64, w*64+64)
// (breg = 32 f16x8 = 128 VGPRs; ~220 unified regs, cap 256 at 2 waves/SIMD).
// __launch_bounds__(256,2) -> 2 INDEPENDENT blocks/CU: decoupled barrier
// domains let block B's MFMAs fill block A's barrier/epilogue bubbles (m114
// overlap) - the thing R12's single 8-wave block structurally could not do.
// MFMA swapped operands: D[w2col][pair]; per-lane 16-col fma chain +
// shfl_xor(16,32); relu(x+b2)*w3 = max(x,-b2)*w3 + Kc.
// ---------------------------------------------------------------------------
#define GRID_MAIN 512
#define KITERS 32

__global__ __launch_bounds__(256, 2) void pairmlp(
    const _Float16* __restrict__ hA, const _Float16* __restrict__ hB,
    const _Float16* __restrict__ W2t, const float* __restrict__ b2,
    const float* __restrict__ W3, const float* __restrict__ b3,
    float* __restrict__ out) {
  __shared__ __align__(16) short h1[2][32 * 256];  // 2 x 16 KB, swizzled f16
  __shared__ float red[2][4][32];                  // partials, dbuf by parity

  const int tid  = threadIdx.x;
  const int lane = tid & 63;
  const int w    = tid >> 6;   // wave 0..3
  const int g    = lane >> 4;  // 0..3
  const int lr   = lane & 15;
  const int bid  = blockIdx.x;
  const int bb    = bid >> 8;               // batch
  const int m0    = ((bid >> 3) & 31) * 16; // fixed per block
  const int nbase = bid & 7;                // 0..7

  // ---- persistent W2 fragments (A-operand): 8 ks x 4 ct = 128 VGPRs ----
  f16x8 breg[8][4];
#pragma unroll
  for (int ks = 0; ks < 8; ks++)
#pragma unroll
    for (int ct = 0; ct < 4; ct++) {
      const int col = w * 64 + ct * 16 + lr;
      breg[ks][ct] =
          *reinterpret_cast<const f16x8*>(&W2t[col * HH + ks * 32 + g * 8]);
    }
  // ---- per-lane epilogue constants, PACKED f16: this lane's 16 w2-cols ----
  f16x8 nb2h[2], w3h[2];   // 8 + 8 VGPRs
  float Kc = 0.f;
#pragma unroll
  for (int i = 0; i < 16; i++) {
    const int col = w * 64 + (i >> 2) * 16 + g * 4 + (i & 3);
    const float bv = b2[col], wv = W3[col];
    nb2h[i >> 3][i & 7] = (_Float16)(-bv);
    w3h[i >> 3][i & 7]  = (_Float16)wv;
    Kc = fmaf(bv, wv, Kc);
  }
  const float b3v = b3[0];

  const int p = tid >> 3;  // 0..31: pair row for construction
  const int c = tid & 7;   // k-chunk of 32

  // ---- loop-invariant hB chunk (f16, 16 VGPRs) ----
  F16x8 hbr[4];
  {
    const _Float16* hBp = hB + ((size_t)(bb * NN + m0 + (p & 15))) * HH + c * 32;
#pragma unroll
    for (int q = 0; q < 4; q++)
      hbr[q].v = *reinterpret_cast<const f16x8*>(hBp + q * 8);
  }
  const _Float16* hAbase = hA + ((size_t)(bb * NN + (p >> 4))) * HH + c * 32;

  auto loadA = [&](int n0, F16x8* av) {
    const _Float16* hAp = hAbase + (size_t)n0 * HH;
#pragma unroll
    for (int q = 0; q < 4; q++)
      av[q].v = *reinterpret_cast<const f16x8*>(hAp + q * 8);
  };
  auto build = [&](const F16x8* av, int buf) {
    const f16x8 zero8 = {};
#pragma unroll
    for (int q = 0; q < 4; q++) {
      F16x8 r;
      r.v = __builtin_elementwise_max(av[q].v + hbr[q].v, zero8);
      const int addr = (p * 512 + c * 64 + q * 16) ^ ((p & 7) << 4);
      *reinterpret_cast<i32x4*>(reinterpret_cast<char*>(h1[buf]) + addr) = r.i;
    }
  };

  // prologue: construct tile k=0 into buffer 0
  {
    F16x8 av[4];
    loadA(2 * nbase, av);
    build(av, 0);
  }

  for (int k = 0; k < KITERS; k++) {
    const int cur = k & 1;
    const int n0  = 2 * (nbase + 8 * k);
    __syncthreads();  // h1[cur] + red[cur^1] ready; WAR on h1[cur^1] resolved

    // issue next tile's hA loads early (hidden under MFMA)
    F16x8 av[4];
    if (k < KITERS - 1) loadA(n0 + 16, av);

    // store previous iter's reduced outputs (ordered by the barrier above)
    if (k > 0 && tid < 32) {
      const int pb = cur ^ 1;
      const float v = red[pb][0][tid] + red[pb][1][tid] + red[pb][2][tid] +
                      red[pb][3][tid] + b3v;
      const int n = (n0 - 16) + (tid >> 4);
      out[((size_t)(bb * NN + n)) * NN + m0 + (tid & 15)] = v;
    }

    // ---- MFMA (swapped operands): D[w2col][pair], 64 MFMAs/wave ----
    f32x4 acc[2][4];
#pragma unroll
    for (int rt = 0; rt < 2; rt++)
#pragma unroll
      for (int ct = 0; ct < 4; ct++) acc[rt][ct] = (f32x4){0.f, 0.f, 0.f, 0.f};
#pragma unroll
    for (int ks = 0; ks < 8; ks++) {
      f16x8 afrag[2];
#pragma unroll
      for (int rt = 0; rt < 2; rt++) {
        const int row  = rt * 16 + lr;
        const int addr = (row * 512 + ks * 64 + g * 16) ^ ((row & 7) << 4);
        afrag[rt] = *reinterpret_cast<const f16x8*>(
            reinterpret_cast<const char*>(h1[cur]) + addr);
      }
#pragma unroll
      for (int rt = 0; rt < 2; rt++)
#pragma unroll
        for (int ct = 0; ct < 4; ct++)
          acc[rt][ct] = __builtin_amdgcn_mfma_f32_16x16x32_f16(
              breg[ks][ct], afrag[rt], acc[rt][ct], 0, 0, 0);
    }

    // construct next tile into the other buffer
    if (k < KITERS - 1) build(av, cur ^ 1);

    // ---- epilogue: per-lane 16-col fma chain + shfl_xor(16,32) reduce ----
    float s[2];
#pragma unroll
    for (int rt = 0; rt < 2; rt++) {
      float t = Kc;
#pragma unroll
      for (int ct = 0; ct < 4; ct++)
#pragma unroll
        for (int r = 0; r < 4; r++) {
          const int i = ct * 4 + r;
          const float nb = (float)nb2h[i >> 3][i & 7];
          const float wv = (float)w3h[i >> 3][i & 7];
          t = fmaf(fmaxf(acc[rt][ct][r], nb), wv, t);
        }
      t += __shfl_xor(t, 16);
      t += __shfl_xor(t, 32);
      s[rt] = t;
    }
    if (lane < 16) {
      red[cur][w][lane]      = s[0];  // pair row = lane      (n = n0)
      red[cur][w][16 + lane] = s[1];  // pair row = 16 + lane (n = n0+1)
    }
  }

  // tail: store the last iter's outputs
  __syncthreads();
  if (tid < 32) {
    const int pb = (KITERS - 1) & 1;
    const float v = red[pb][0][tid] + red[pb][1][tid] + red[pb][2][tid] +
                    red[pb][3][tid] + b3v;
    const int n = 2 * (nbase + 8 * (KITERS - 1)) + (tid >> 4);
    out[(size_t)(bb * NN + n) * NN + m0 + (tid & 15)] = v;
  }
}

// ---------------------------------------------------------------------------
extern "C" void kernel_launch(void* const* d_in, const int* in_sizes, int n_in,
                              void* d_out, int out_size, void* d_ws, size_t ws_size,
                              hipStream_t stream) {
  const float* PhiA = (const float*)d_in[0];
  const float* PhiB = (const float*)d_in[1];
  const float* W1   = (const float*)d_in[2];
  const float* b1   = (const float*)d_in[3];
  const float* W2   = (const float*)d_in[4];
  const float* b2   = (const float*)d_in[5];
  const float* W3   = (const float*)d_in[6];
  const float* b3   = (const float*)d_in[7];
  float* out = (float*)d_out;

  char* ws = (char*)d_ws;
  _Float16* hA  = (_Float16*)ws;                    // 512 KB
  _Float16* hB  = (_Float16*)(ws + (512u << 10));   // 512 KB
  _Float16* W2t = (_Float16*)(ws + (1024u << 10));  // 128 KB

  hipLaunchKernelGGL(stage1, dim3(S1_BLOCKS + 8), dim3(256), 0, stream,
                     PhiA, PhiB, W1, b1, W2, hA, hB, W2t);
  hipLaunchKernelGGL(pairmlp, dim3(GRID_MAIN), dim3(256), 0, stream,
                     hA, hB, W2t, b2, W3, b3, out);
}